// Round 4
// baseline (151.587 us; speedup 1.0000x reference)
//
#include <hip/hip_runtime.h>
#include <hip/hip_fp16.h>
#include <math.h>

#define SEQ   4096
#define DIM   128
#define UDIM  64
#define BATCH 4
#define BS    (BATCH*SEQ)

typedef _Float16 h8 __attribute__((ext_vector_type(8)));
typedef _Float16 h2 __attribute__((ext_vector_type(2)));
typedef float    f4 __attribute__((ext_vector_type(4)));

#define MFMA16(a,b,c) __builtin_amdgcn_mfma_f32_16x16x32_f16((a),(b),(c),0,0,0)

__device__ __forceinline__ h2 pk2(float a, float b) {
  return __builtin_bit_cast(h2, __builtin_amdgcn_cvt_pkrtz(a, b));
}

// Strides chosen so lane-to-lane word stride ≡ 4 (mod 32): conflict-free b128.
#define WT_STRIDE 272   // bytes per n-row of W^T (136 halves)
#define VB_STRIDE 144   // v-bounce / VTs / Ps row stride (72 halves)
#define L2E 1.44269504088896f

// butterfly max over 16-lane groups on packed f16x2
__device__ __forceinline__ h2 pkmax_bcast16(h2 v) {
  h2 o;
  o = __builtin_bit_cast(h2, __builtin_amdgcn_ds_swizzle(__builtin_bit_cast(int, v), 0x041F));
  v = __builtin_elementwise_max(v, o);
  o = __builtin_bit_cast(h2, __builtin_amdgcn_ds_swizzle(__builtin_bit_cast(int, v), 0x081F));
  v = __builtin_elementwise_max(v, o);
  o = __builtin_bit_cast(h2, __builtin_amdgcn_ds_swizzle(__builtin_bit_cast(int, v), 0x101F));
  v = __builtin_elementwise_max(v, o);
  o = __builtin_bit_cast(h2, __builtin_amdgcn_ds_swizzle(__builtin_bit_cast(int, v), 0x201F));
  v = __builtin_elementwise_max(v, o);
  return v;
}

// ---------------- Kernel A: qkv projection via MFMA ----------------
// grid (BS/64, 3), block 256 (4 waves x 16 rows). W staged f16-transposed in
// LDS (coalesced loads, conflict-free b128 frag reads). Register-lean: no
// 128-load gather burst (R3's proj spill suspect).
__global__ __launch_bounds__(256, 3) void proj_mfma(
    const float* __restrict__ x,
    const float* __restrict__ Wq, const float* __restrict__ bq,
    const float* __restrict__ Wk, const float* __restrict__ bk,
    const float* __restrict__ Wv, const float* __restrict__ bv,
    _Float16* __restrict__ qf, _Float16* __restrict__ kf, _Float16* __restrict__ vt)
{
  const int proj = blockIdx.y;
  const float* __restrict__ W    = proj==0 ? Wq : (proj==1 ? Wk : Wv);
  const float* __restrict__ bias = proj==0 ? bq : (proj==1 ? bk : bv);
  const int tid  = threadIdx.x;
  const int lane = tid & 63, wv = tid >> 6;
  const int n = lane & 15, quad = lane >> 4;
  const int r0 = blockIdx.x * 64;

  __shared__ __align__(16) char lds[UDIM * WT_STRIDE];  // W^T; reused as v-bounce

  // ---- stage W^T[n][k] f16 (stride 136 halves) ----
  #pragma unroll
  for (int i = 0; i < 8; ++i) {
    const int idx = i*256 + tid;            // 0..2047
    const int nn  = idx & 63;
    const int k4  = (idx >> 6) * 4;         // 0..124
    const float w0 = W[(k4+0)*UDIM + nn];   // coalesced per k-row
    const float w1 = W[(k4+1)*UDIM + nn];
    const float w2 = W[(k4+2)*UDIM + nn];
    const float w3 = W[(k4+3)*UDIM + nn];
    int2 wd;
    wd.x = __builtin_bit_cast(int, pk2(w0, w1));
    wd.y = __builtin_bit_cast(int, pk2(w2, w3));
    *(int2*)(lds + nn*WT_STRIDE + k4*2) = wd;   // b64, <=2-way banks
  }
  __syncthreads();

  // ---- A-fragments: x rows fp32 -> f16 packed ----
  const int row = r0 + wv*16 + n;
  h8 xa[4];
  #pragma unroll
  for (int ks = 0; ks < 4; ++ks) {
    const float* xp = x + (size_t)row*DIM + ks*32 + quad*8;
    const f4 a = *(const f4*)xp, b = *(const f4*)(xp + 4);
    int4 pkd;
    pkd.x = __builtin_bit_cast(int, pk2(a[0], a[1]));
    pkd.y = __builtin_bit_cast(int, pk2(a[2], a[3]));
    pkd.z = __builtin_bit_cast(int, pk2(b[0], b[1]));
    pkd.w = __builtin_bit_cast(int, pk2(b[2], b[3]));
    xa[ks] = __builtin_bit_cast(h8, pkd);
  }

  f4 acc[4];
  #pragma unroll
  for (int nt = 0; nt < 4; ++nt) acc[nt] = (f4){0.f,0.f,0.f,0.f};

  #pragma unroll
  for (int ks = 0; ks < 4; ++ks)
    #pragma unroll
    for (int nt = 0; nt < 4; ++nt) {
      const h8 wf = *(const h8*)(lds + (nt*16 + n)*WT_STRIDE + (ks*32 + quad*8)*2);
      acc[nt] = MFMA16(xa[ks], wf, acc[nt]);
    }

  #pragma unroll
  for (int nt = 0; nt < 4; ++nt) {
    const float bb = bias[nt*16 + n];
    #pragma unroll
    for (int r = 0; r < 4; ++r) acc[nt][r] += bb;
  }

  if (proj < 2) {
    // q,k -> [s][u] f16; DPP pair-swap + v_perm -> b32 stores
    _Float16* __restrict__ out = (proj == 0) ? qf : kf;
    const int par = lane & 1;
    const unsigned sel = par ? 0x03020706u : 0x05040100u;
    #pragma unroll
    for (int nt = 0; nt < 4; ++nt)
      #pragma unroll
      for (int p = 0; p < 2; ++p) {
        const int r = 2*p;
        unsigned A  = __builtin_bit_cast(unsigned, pk2(acc[nt][r], acc[nt][r+1]));
        unsigned Bs = (unsigned)__builtin_amdgcn_mov_dpp((int)A, 0xB1, 0xF, 0xF, true);
        unsigned w  = __builtin_amdgcn_perm(Bs, A, sel);
        const int orow = r0 + wv*16 + 4*quad + r + par;
        const int ocol = nt*16 + n - par;   // even
        *(unsigned*)((char*)out + ((size_t)orow*UDIM + ocol)*2) = w;
      }
  } else {
    // v -> v^T [u][s] via LDS bounce (reuse lds buffer)
    __syncthreads();   // all frag reads done before overwrite
    #pragma unroll
    for (int nt = 0; nt < 4; ++nt)
      #pragma unroll
      for (int p = 0; p < 2; ++p) {
        const int r = 2*p;
        const int u = nt*16 + n;
        const int lrow = wv*16 + 4*quad + r;   // rows r, r+1 packed
        *(unsigned*)(lds + u*VB_STRIDE + lrow*2) =
            __builtin_bit_cast(unsigned, pk2(acc[nt][r], acc[nt][r+1]));
      }
    __syncthreads();
    const int b  = r0 / SEQ;
    const int s0 = r0 % SEQ;
    #pragma unroll
    for (int i = 0; i < 2; ++i) {
      const int e = tid + 256*i;         // 0..511
      const int u = e >> 3, ch = e & 7;
      h8 v = *(const h8*)(lds + u*VB_STRIDE + ch*16);
      *(h8*)(vt + ((size_t)b*UDIM + u)*SEQ + s0 + ch*8) = v;
    }
  }
}

// ---------------- Kernel B: flash attention, f16 MFMA ----------------
// grid (SEQ/64, BATCH, nsplit), block 256 (4 waves x 16 q-rows).
// 1024 blocks -> 4/CU, 16 waves/CU. K B-frags direct from global; V^T in LDS;
// P LDS round-trip; l via ones-column.
__global__ __launch_bounds__(256, 4) void flash_attn_f16(
    const _Float16* __restrict__ qf, const _Float16* __restrict__ kf,
    const _Float16* __restrict__ vt,
    float* __restrict__ opart, float* __restrict__ Mp, float* __restrict__ Lp,
    int nkt)
{
  const int qt = blockIdx.x, b = blockIdx.y, sp = blockIdx.z;
  const _Float16* __restrict__ qb = qf + (size_t)b*SEQ*UDIM;
  const _Float16* __restrict__ kb = kf + (size_t)b*SEQ*UDIM;
  const _Float16* __restrict__ vb = vt + (size_t)b*UDIM*SEQ;

  __shared__ __align__(16) char VTs[UDIM * VB_STRIDE];  // 9216 B
  __shared__ __align__(16) char Ps [64   * VB_STRIDE];  // 9216 B

  const int tid = threadIdx.x;
  const int lane = tid & 63, wv = tid >> 6;
  const int n = lane & 15, quad = lane >> 4;
  const int wrow0 = wv * 16;
  const int qrow0 = qt * 64;

  h8 qa[2];
  #pragma unroll
  for (int ks = 0; ks < 2; ++ks)
    qa[ks] = *(const h8*)(qb + (size_t)(qrow0 + wrow0 + n)*UDIM + ks*32 + quad*8);

  f4 O[5];
  #pragma unroll
  for (int c = 0; c < 5; ++c) O[c] = (f4){0.f,0.f,0.f,0.f};
  float M[4];
  #pragma unroll
  for (int r = 0; r < 4; ++r) M[r] = -1e30f;

  h8 ones;
  { const _Float16 o = (n == 0) ? (_Float16)1.0f : (_Float16)0.0f;
    #pragma unroll
    for (int j = 0; j < 8; ++j) ones[j] = o; }

  const int par = lane & 1;
  const unsigned psel = par ? 0x03020706u : 0x05040100u;

  const int kt0 = sp * nkt;
  for (int kt = kt0; kt < kt0 + nkt; ++kt) {
    __syncthreads();
    #pragma unroll
    for (int i = 0; i < 2; ++i) {
      const int e = tid + 256*i, u = e >> 3, kc = e & 7;
      *(h8*)(VTs + u*VB_STRIDE + kc*16) =
          *(const h8*)(vb + (size_t)u*SEQ + kt*64 + kc*8);
    }
    __syncthreads();

    // ---- QK^T ----
    f4 S[4];
    #pragma unroll
    for (int nt = 0; nt < 4; ++nt) S[nt] = (f4){0.f,0.f,0.f,0.f};
    #pragma unroll
    for (int nt = 0; nt < 4; ++nt) {
      const _Float16* kp = kb + (size_t)(kt*64 + nt*16 + n)*UDIM + quad*8;
      const h8 k0 = *(const h8*)kp;
      const h8 k1 = *(const h8*)(kp + 32);
      S[nt] = MFMA16(qa[0], k0, S[nt]);
      S[nt] = MFMA16(qa[1], k1, S[nt]);
    }

    // ---- per-row max + online-softmax state ----
    float alpha[4];
    {
      float rm[4];
      #pragma unroll
      for (int r = 0; r < 4; ++r)
        rm[r] = fmaxf(fmaxf(S[0][r], S[1][r]), fmaxf(S[2][r], S[3][r]));
      #pragma unroll
      for (int p = 0; p < 2; ++p) {
        h2 v = pk2(rm[2*p], rm[2*p+1]);
        v = pkmax_bcast16(v);
        #pragma unroll
        for (int t = 0; t < 2; ++t) {
          const int r = 2*p + t;
          const float rl = (float)v[t] * L2E;
          const float mo = M[r];
          const float mn = fmaxf(mo, rl);
          alpha[r] = exp2f(mo - mn);
          M[r] = mn;
        }
      }
    }

    // ---- P = exp2(S*L2E - M) -> Ps (f16, A-layout rows) ----
    #pragma unroll
    for (int nt = 0; nt < 4; ++nt) {
      #pragma unroll
      for (int r = 0; r < 4; ++r)
        S[nt][r] = exp2f(fmaf(S[nt][r], L2E, -M[r]));
      #pragma unroll
      for (int p = 0; p < 2; ++p) {
        const int r = 2*p;
        unsigned A  = __builtin_bit_cast(unsigned, pk2(S[nt][r], S[nt][r+1]));
        unsigned Bs = (unsigned)__builtin_amdgcn_mov_dpp((int)A, 0xB1, 0xF, 0xF, true);
        unsigned w  = __builtin_amdgcn_perm(Bs, A, psel);
        const int prow = wrow0 + 4*quad + r + par;
        const int pcol = nt*16 + n - par;
        *(unsigned*)(Ps + prow*VB_STRIDE + pcol*2) = w;
      }
    }

    // ---- rescale O ----
    #pragma unroll
    for (int c = 0; c < 5; ++c)
      #pragma unroll
      for (int r = 0; r < 4; ++r)
        O[c][r] *= alpha[r];

    // ---- PV + l (same-wave DS ordering; no barrier needed) ----
    #pragma unroll
    for (int ks = 0; ks < 2; ++ks) {
      const h8 pa = *(const h8*)(Ps + (wrow0 + n)*VB_STRIDE + ks*64 + quad*16);
      #pragma unroll
      for (int nt = 0; nt < 4; ++nt) {
        const h8 vf = *(const h8*)(VTs + (nt*16 + n)*VB_STRIDE + ks*64 + quad*16);
        O[nt] = MFMA16(pa, vf, O[nt]);
      }
      O[4] = MFMA16(pa, ones, O[4]);
    }
  }

  // ---- epilogue ----
  const size_t rowbase = (size_t)sp*BS + (size_t)b*SEQ + qrow0;
  #pragma unroll
  for (int nt = 0; nt < 4; ++nt)
    #pragma unroll
    for (int r = 0; r < 4; ++r) {
      const int row = wrow0 + 4*quad + r;
      opart[(rowbase + row)*UDIM + nt*16 + n] = O[nt][r];
    }
  if (n == 0) {
    #pragma unroll
    for (int r = 0; r < 4; ++r) {
      const int row = wrow0 + 4*quad + r;
      Mp[rowbase + row] = M[r];
      Lp[rowbase + row] = O[4][r];
    }
  }
}

// ---------------- Kernel C: merge key-split partials (f4) ----------------
__global__ __launch_bounds__(256) void merge_out(
    const float* __restrict__ opart, const float* __restrict__ Mp,
    const float* __restrict__ Lp, float* __restrict__ out, int nsplit)
{
  const int tid = threadIdx.x;
  const int row = blockIdx.x*16 + (tid >> 4);
  const int u4  = (tid & 15) * 4;
  float M = -1e30f;
  for (int s = 0; s < nsplit; ++s) M = fmaxf(M, Mp[(size_t)s*BS + row]);
  f4 num = (f4){0.f,0.f,0.f,0.f};
  float den = 0.f;
  for (int s = 0; s < nsplit; ++s) {
    const float w = exp2f(Mp[(size_t)s*BS + row] - M);
    den += w * Lp[(size_t)s*BS + row];
    const f4 op = *(const f4*)(opart + ((size_t)s*BS + row)*UDIM + u4);
    num += w * op;
  }
  const float dinv = 1.f / den;
  *(f4*)(out + (size_t)row*UDIM + u4) = num * dinv;
}

extern "C" void kernel_launch(void* const* d_in, const int* in_sizes, int n_in,
                              void* d_out, int out_size, void* d_ws, size_t ws_size,
                              hipStream_t stream) {
  (void)in_sizes; (void)n_in; (void)out_size;
  const float* x  = (const float*)d_in[0];
  const float* Wq = (const float*)d_in[1];
  const float* bq = (const float*)d_in[2];
  const float* Wk = (const float*)d_in[3];
  const float* bk = (const float*)d_in[4];
  const float* Wv = (const float*)d_in[5];
  const float* bv = (const float*)d_in[6];
  float* out = (float*)d_out;

  char* ws = (char*)d_ws;
  const size_t fBytes = (size_t)BS * UDIM * 2;
  auto need = [](int nsp) {
    return (size_t)3*BS*UDIM*2 + (size_t)nsp*BS*4*2 + (size_t)nsp*BS*UDIM*4;
  };
  int nsplit;
  if      (ws_size >= need(4)) nsplit = 4;
  else if (ws_size >= need(2)) nsplit = 2;
  else                         nsplit = 1;

  _Float16* qf = (_Float16*)(ws);
  _Float16* kf = (_Float16*)(ws + fBytes);
  _Float16* vt = (_Float16*)(ws + 2*fBytes);
  float* Mp    = (float*)(ws + 3*fBytes);
  float* Lp    = (float*)(ws + 3*fBytes + (size_t)nsplit*BS*4);
  float* opart = (float*)(ws + 3*fBytes + (size_t)nsplit*BS*8);

  proj_mfma<<<dim3(BS/64, 3), 256, 0, stream>>>(x, Wq, bq, Wk, bk, Wv, bv, qf, kf, vt);
  flash_attn_f16<<<dim3(SEQ/64, BATCH, nsplit), 256, 0, stream>>>(
      qf, kf, vt, opart, Mp, Lp, (SEQ/64)/nsplit);
  merge_out<<<dim3(BS/16), 256, 0, stream>>>(opart, Mp, Lp, out, nsplit);
}